// Round 4
// baseline (1660.609 us; speedup 1.0000x reference)
//
#include <hip/hip_runtime.h>

#define NN 200000
#define NE 6400000
#define FIN 512
#define HID 16
#define NC 7
#define NB 782        // ceil(NN/256); also bucket count (256 nodes/bucket)
#define K  782        // bucket = dst >> 8
#define CH 8192       // edges per block (count + fill)
#define EB 782        // ceil(NE/CH)
#define KC 32

// ============ bucket count: LDS histogram of dst>>8 ============

__global__ __launch_bounds__(256) void k_bcount(const int* __restrict__ dst, int* __restrict__ bucket_total) {
    __shared__ int hist[K];
    int tid = threadIdx.x;
    long e0 = (long)blockIdx.x * CH;
    int cnt = (int)min((long)CH, (long)NE - e0);
    for (int i = tid; i < K; i += 256) hist[i] = 0;
    __syncthreads();
    for (int i = tid; i < cnt; i += 256) atomicAdd(&hist[dst[e0 + i] >> 8], 1);
    __syncthreads();
    for (int b = tid; b < K; b += 256) {
        int h = hist[b];
        if (h) atomicAdd(&bucket_total[b], h);
    }
}

// ============ bucket base scan ============

__global__ __launch_bounds__(1024) void k_bscan(const int* __restrict__ bucket_total,
                                                int* __restrict__ bucket_base, int* __restrict__ bucket_cursor) {
    __shared__ int tmp[1024];
    int i = threadIdx.x;
    int v = (i < K) ? bucket_total[i] : 0;
    tmp[i] = v;
    __syncthreads();
    #pragma unroll
    for (int off = 1; off < 1024; off <<= 1) {
        int t = (i >= off) ? tmp[i - off] : 0;
        __syncthreads();
        tmp[i] += t;
        __syncthreads();
    }
    if (i < K) {
        int base = tmp[i] - v;
        bucket_base[i] = base;
        bucket_cursor[i] = base;
    }
    if (i == K - 1) bucket_base[K] = tmp[i];
}

// ============ bucket fill: LDS bin-sort stage -> COALESCED run writes (R2-proven shape) ============

__global__ __launch_bounds__(256) void k_bfill(const int* __restrict__ src, const int* __restrict__ dst,
                                               int* __restrict__ bucket_cursor, unsigned int* __restrict__ bwords) {
    __shared__ int hist[K];
    __shared__ int ofs0[K];
    __shared__ int gb2[K];
    __shared__ int ptmp[256];
    __shared__ unsigned long long stage[CH];
    int tid = threadIdx.x;
    long e0 = (long)blockIdx.x * CH;
    int cnt = (int)min((long)CH, (long)NE - e0);

    for (int i = tid; i < K; i += 256) hist[i] = 0;
    __syncthreads();
    for (int i = tid; i < cnt; i += 256) atomicAdd(&hist[dst[e0 + i] >> 8], 1);
    __syncthreads();

    // block-exclusive scan over K bins: thread t owns bins 4t..4t+3
    int b0 = tid * 4;
    int h0 = (b0 + 0 < K) ? hist[b0 + 0] : 0;
    int h1 = (b0 + 1 < K) ? hist[b0 + 1] : 0;
    int h2 = (b0 + 2 < K) ? hist[b0 + 2] : 0;
    int h3 = (b0 + 3 < K) ? hist[b0 + 3] : 0;
    int s = h0 + h1 + h2 + h3;
    ptmp[tid] = s;
    __syncthreads();
    #pragma unroll
    for (int off = 1; off < 256; off <<= 1) {
        int t = (tid >= off) ? ptmp[tid - off] : 0;
        __syncthreads();
        ptmp[tid] += t;
        __syncthreads();
    }
    int run = ptmp[tid] - s;
    if (b0 + 0 < K) { ofs0[b0 + 0] = run; run += h0; }
    if (b0 + 1 < K) { ofs0[b0 + 1] = run; run += h1; }
    if (b0 + 2 < K) { ofs0[b0 + 2] = run; run += h2; }
    if (b0 + 3 < K) { ofs0[b0 + 3] = run; run += h3; }
    __syncthreads();

    for (int b = tid; b < K; b += 256) {
        int h = hist[b];
        int g = h ? atomicAdd(&bucket_cursor[b], h) : 0;
        gb2[b] = g - ofs0[b];
    }
    __syncthreads();
    for (int b = tid; b < K; b += 256) hist[b] = 0;
    __syncthreads();

    for (int i = tid; i < cnt; i += 256) {
        int d = dst[e0 + i];
        int sv = src[e0 + i];
        int bin = d >> 8;
        int r = atomicAdd(&hist[bin], 1);
        unsigned int word = ((unsigned int)(d & 255) << 24) | (unsigned int)sv;  // src < 2^24
        stage[ofs0[bin] + r] = ((unsigned long long)(unsigned int)d << 32) | word;
    }
    __syncthreads();
    // coalesced: consecutive i -> consecutive bwords addresses within each run
    for (int i = tid; i < cnt; i += 256) {
        unsigned long long p = stage[i];
        int bin = (int)(p >> 40);          // d >> 8
        bwords[gb2[bin] + i] = (unsigned int)p;
    }
}

// ============ per-bucket degree -> dinv (no sort, no csr) ============

__global__ __launch_bounds__(256) void k_deg(const unsigned int* __restrict__ bwords,
                                             const int* __restrict__ bucket_base, float* __restrict__ dinv) {
    __shared__ int cnt[256];
    int b = blockIdx.x;
    int tid = threadIdx.x;
    cnt[tid] = 0;
    __syncthreads();
    int p0 = bucket_base[b];
    int p1 = bucket_base[b + 1];
    for (int i = p0 + tid; i < p1; i += 256) atomicAdd(&cnt[bwords[i] >> 24], 1);
    __syncthreads();
    int n = (b << 8) + tid;
    if (n < NN) dinv[n] = rsqrtf((float)(cnt[tid] + 1));   // +1 self-loop
}

// ============ gemm1: h1s = (x @ W1) * dinv ============

__global__ __launch_bounds__(256) void k_gemm1(const float* __restrict__ x, const float* __restrict__ W1,
                                               const float* __restrict__ dinv, float* __restrict__ h1s) {
    __shared__ float xs[KC][257];
    const int tid = threadIdx.x;
    const int row0 = blockIdx.x * 256;
    const int row = row0 + tid;
    float dv = (row < NN) ? dinv[row] : 1.f;
    float acc[HID];
    #pragma unroll
    for (int c = 0; c < HID; ++c) acc[c] = 0.f;

    for (int k0 = 0; k0 < FIN; k0 += KC) {
        __syncthreads();
        #pragma unroll
        for (int j = 0; j < 8; ++j) {
            int f = tid + 256 * j;
            int r = f >> 3;
            int kq = f & 7;
            int gr = row0 + r;
            float4 v = make_float4(0.f, 0.f, 0.f, 0.f);
            if (gr < NN) v = *(const float4*)(x + (size_t)gr * FIN + k0 + kq * 4);
            xs[kq * 4 + 0][r] = v.x;
            xs[kq * 4 + 1][r] = v.y;
            xs[kq * 4 + 2][r] = v.z;
            xs[kq * 4 + 3][r] = v.w;
        }
        __syncthreads();
        #pragma unroll 4
        for (int k = 0; k < KC; ++k) {
            float xv = xs[k][tid];
            const float4* w = (const float4*)(W1 + (size_t)(k0 + k) * HID);
            float4 w0 = w[0], w1 = w[1], w2 = w[2], w3 = w[3];
            acc[0]  = fmaf(xv, w0.x, acc[0]);  acc[1]  = fmaf(xv, w0.y, acc[1]);
            acc[2]  = fmaf(xv, w0.z, acc[2]);  acc[3]  = fmaf(xv, w0.w, acc[3]);
            acc[4]  = fmaf(xv, w1.x, acc[4]);  acc[5]  = fmaf(xv, w1.y, acc[5]);
            acc[6]  = fmaf(xv, w1.z, acc[6]);  acc[7]  = fmaf(xv, w1.w, acc[7]);
            acc[8]  = fmaf(xv, w2.x, acc[8]);  acc[9]  = fmaf(xv, w2.y, acc[9]);
            acc[10] = fmaf(xv, w2.z, acc[10]); acc[11] = fmaf(xv, w2.w, acc[11]);
            acc[12] = fmaf(xv, w3.x, acc[12]); acc[13] = fmaf(xv, w3.y, acc[13]);
            acc[14] = fmaf(xv, w3.z, acc[14]); acc[15] = fmaf(xv, w3.w, acc[15]);
        }
    }
    if (row < NN) {
        float4* o = (float4*)(h1s + (size_t)row * HID);
        o[0] = make_float4(acc[0] * dv, acc[1] * dv, acc[2] * dv, acc[3] * dv);
        o[1] = make_float4(acc[4] * dv, acc[5] * dv, acc[6] * dv, acc[7] * dv);
        o[2] = make_float4(acc[8] * dv, acc[9] * dv, acc[10] * dv, acc[11] * dv);
        o[3] = make_float4(acc[12] * dv, acc[13] * dv, acc[14] * dv, acc[15] * dv);
    }
}

// ============ agg1 per bucket: LDS acc + ds_add_f32, epilogue bias/relu/W2/prescale ============
// acc padded to 17 floats/node: bank=(17*loc+c)%32 spreads; ds_add_f32 is no-return (non-blocking)

__device__ __forceinline__ void atom16(float* A, const float* p) {
    const float4* q = (const float4*)p;
    float4 a = q[0], b = q[1], c = q[2], d = q[3];
    atomicAdd(&A[0],  a.x); atomicAdd(&A[1],  a.y); atomicAdd(&A[2],  a.z); atomicAdd(&A[3],  a.w);
    atomicAdd(&A[4],  b.x); atomicAdd(&A[5],  b.y); atomicAdd(&A[6],  b.z); atomicAdd(&A[7],  b.w);
    atomicAdd(&A[8],  c.x); atomicAdd(&A[9],  c.y); atomicAdd(&A[10], c.z); atomicAdd(&A[11], c.w);
    atomicAdd(&A[12], d.x); atomicAdd(&A[13], d.y); atomicAdd(&A[14], d.z); atomicAdd(&A[15], d.w);
}

__global__ __launch_bounds__(256) void k_agg1b(const unsigned int* __restrict__ bwords,
                                               const int* __restrict__ bucket_base,
                                               const float* __restrict__ h1s, const float* __restrict__ dinv,
                                               const float* __restrict__ b1, const float* __restrict__ W2,
                                               float* __restrict__ h2s) {
    __shared__ float acc[256 * 17];
    int b = blockIdx.x;
    int tid = threadIdx.x;
    int n = (b << 8) + tid;
    float* A0 = acc + tid * 17;
    if (n < NN) {            // self-loop init: h1s row
        const float4* q = (const float4*)(h1s + (size_t)n * HID);
        float4 a = q[0], bb = q[1], c = q[2], d = q[3];
        A0[0]=a.x; A0[1]=a.y; A0[2]=a.z; A0[3]=a.w;  A0[4]=bb.x; A0[5]=bb.y; A0[6]=bb.z; A0[7]=bb.w;
        A0[8]=c.x; A0[9]=c.y; A0[10]=c.z; A0[11]=c.w; A0[12]=d.x; A0[13]=d.y; A0[14]=d.z; A0[15]=d.w;
    } else {
        #pragma unroll
        for (int c = 0; c < HID; ++c) A0[c] = 0.f;
    }
    __syncthreads();
    int p0 = bucket_base[b];
    int p1 = bucket_base[b + 1];
    int i = p0 + tid;
    for (; i + 256 < p1; i += 512) {
        unsigned int w0 = bwords[i], w1 = bwords[i + 256];
        const float* r0 = h1s + (size_t)(w0 & 0xFFFFFFu) * HID;
        const float* r1 = h1s + (size_t)(w1 & 0xFFFFFFu) * HID;
        atom16(acc + (w0 >> 24) * 17, r0);
        atom16(acc + (w1 >> 24) * 17, r1);
    }
    if (i < p1) {
        unsigned int w = bwords[i];
        atom16(acc + (w >> 24) * 17, h1s + (size_t)(w & 0xFFFFFFu) * HID);
    }
    __syncthreads();
    if (n < NN) {
        float dv = dinv[n];
        float h[HID];
        #pragma unroll
        for (int c = 0; c < HID; ++c) h[c] = fmaxf(fmaf(dv, A0[c], b1[c]), 0.f);
        float z[8];
        #pragma unroll
        for (int j = 0; j < NC; ++j) {
            float t = 0.f;
            #pragma unroll
            for (int c = 0; c < HID; ++c) t = fmaf(h[c], W2[c * NC + j], t);
            z[j] = t * dv;
        }
        z[7] = 0.f;
        float4* o = (float4*)(h2s + (size_t)n * 8);
        o[0] = make_float4(z[0], z[1], z[2], z[3]);
        o[1] = make_float4(z[4], z[5], z[6], z[7]);
    }
}

// ============ agg2 per bucket: LDS acc (pad 9) + bias -> out ============

__device__ __forceinline__ void atom8(float* A, const float* p) {
    const float4* q = (const float4*)p;
    float4 a = q[0], b = q[1];
    atomicAdd(&A[0], a.x); atomicAdd(&A[1], a.y); atomicAdd(&A[2], a.z); atomicAdd(&A[3], a.w);
    atomicAdd(&A[4], b.x); atomicAdd(&A[5], b.y); atomicAdd(&A[6], b.z);
}

__global__ __launch_bounds__(256) void k_agg2b(const unsigned int* __restrict__ bwords,
                                               const int* __restrict__ bucket_base,
                                               const float* __restrict__ h2s, const float* __restrict__ dinv,
                                               const float* __restrict__ b2, float* __restrict__ out) {
    __shared__ float acc[256 * 9];
    int b = blockIdx.x;
    int tid = threadIdx.x;
    int n = (b << 8) + tid;
    float* A0 = acc + tid * 9;
    if (n < NN) {            // self-loop init
        const float4* q = (const float4*)(h2s + (size_t)n * 8);
        float4 a = q[0], bb = q[1];
        A0[0]=a.x; A0[1]=a.y; A0[2]=a.z; A0[3]=a.w; A0[4]=bb.x; A0[5]=bb.y; A0[6]=bb.z; A0[7]=bb.w;
    } else {
        #pragma unroll
        for (int c = 0; c < 8; ++c) A0[c] = 0.f;
    }
    __syncthreads();
    int p0 = bucket_base[b];
    int p1 = bucket_base[b + 1];
    int i = p0 + tid;
    for (; i + 256 < p1; i += 512) {
        unsigned int w0 = bwords[i], w1 = bwords[i + 256];
        const float* r0 = h2s + (size_t)(w0 & 0xFFFFFFu) * 8;
        const float* r1 = h2s + (size_t)(w1 & 0xFFFFFFu) * 8;
        atom8(acc + (w0 >> 24) * 9, r0);
        atom8(acc + (w1 >> 24) * 9, r1);
    }
    if (i < p1) {
        unsigned int w = bwords[i];
        atom8(acc + (w >> 24) * 9, h2s + (size_t)(w & 0xFFFFFFu) * 8);
    }
    __syncthreads();
    if (n < NN) {
        float dv = dinv[n];
        #pragma unroll
        for (int j = 0; j < NC; ++j) out[(size_t)n * NC + j] = fmaf(dv, A0[j], b2[j]);
    }
}

// ============ launch ============

extern "C" void kernel_launch(void* const* d_in, const int* in_sizes, int n_in,
                              void* d_out, int out_size, void* d_ws, size_t ws_size,
                              hipStream_t stream) {
    const float* x  = (const float*)d_in[0];
    const int*   ei = (const int*)d_in[1];
    const float* W1 = (const float*)d_in[2];
    const float* b1 = (const float*)d_in[3];
    const float* W2 = (const float*)d_in[4];
    const float* b2 = (const float*)d_in[5];
    const int* src = ei;
    const int* dst = ei + NE;
    float* out = (float*)d_out;

    char* ws = (char*)d_ws;
    size_t o = 0;
    auto alloc = [&](size_t bytes) {
        char* p = ws + o;
        o = (o + bytes + 255) & ~(size_t)255;
        return p;
    };
    int*   bucket_total  = (int*)alloc((size_t)(K + 1) * 4);
    int*   bucket_base   = (int*)alloc((size_t)(K + 1) * 4);
    int*   bucket_cursor = (int*)alloc((size_t)(K + 1) * 4);
    unsigned int* bwords = (unsigned int*)alloc((size_t)NE * 4);
    float* dinv     = (float*)alloc((size_t)NN * 4);
    float* h1s      = (float*)alloc((size_t)NN * HID * 4);
    float* h2s      = (float*)alloc((size_t)NN * 8 * 4);

    hipMemsetAsync(bucket_total, 0, (size_t)(K + 1) * 4, stream);
    k_bcount<<<EB, 256, 0, stream>>>(dst, bucket_total);
    k_bscan <<<1, 1024, 0, stream>>>(bucket_total, bucket_base, bucket_cursor);
    k_bfill <<<EB, 256, 0, stream>>>(src, dst, bucket_cursor, bwords);
    k_deg   <<<K, 256, 0, stream>>>(bwords, bucket_base, dinv);
    k_gemm1 <<<NB, 256, 0, stream>>>(x, W1, dinv, h1s);
    k_agg1b <<<K, 256, 0, stream>>>(bwords, bucket_base, h1s, dinv, b1, W2, h2s);
    k_agg2b <<<K, 256, 0, stream>>>(bwords, bucket_base, h2s, dinv, b2, out);
}

// Round 5
// 866.215 us; speedup vs baseline: 1.9171x; 1.9171x over previous
//
#include <hip/hip_runtime.h>
#include <hip/hip_fp16.h>

#define NN 200000
#define NE 6400000
#define FIN 512
#define HID 16
#define NC 7
#define NB 782        // ceil(NN/256); also bucket count (256 nodes/bucket)
#define K  782        // bucket = dst >> 8
#define CH 8192       // edges per block (count + fill)
#define EB 782        // ceil(NE/CH)
#define KC 32
#define WMAX 10240    // per-bucket edge cap for LDS sort (mean 8184, sigma ~90 -> 22 sigma margin)

// ---------- fp16 helpers ----------
__device__ __forceinline__ unsigned f2h(float a, float b) {
    __half2 h = __floats2half2_rn(a, b);
    return __builtin_bit_cast(unsigned, h);
}
__device__ __forceinline__ float2 h2f(unsigned u) {
    return __half22float2(__builtin_bit_cast(__half2, u));
}

// ============ bucket count: LDS histogram of dst>>8 ============

__global__ __launch_bounds__(256) void k_bcount(const int* __restrict__ dst, int* __restrict__ bucket_total) {
    __shared__ int hist[K];
    int tid = threadIdx.x;
    long e0 = (long)blockIdx.x * CH;
    int cnt = (int)min((long)CH, (long)NE - e0);
    for (int i = tid; i < K; i += 256) hist[i] = 0;
    __syncthreads();
    for (int i = tid; i < cnt; i += 256) atomicAdd(&hist[dst[e0 + i] >> 8], 1);
    __syncthreads();
    for (int b = tid; b < K; b += 256) {
        int h = hist[b];
        if (h) atomicAdd(&bucket_total[b], h);
    }
}

// ============ bucket base scan ============

__global__ __launch_bounds__(1024) void k_bscan(const int* __restrict__ bucket_total,
                                                int* __restrict__ bucket_base, int* __restrict__ bucket_cursor) {
    __shared__ int tmp[1024];
    int i = threadIdx.x;
    int v = (i < K) ? bucket_total[i] : 0;
    tmp[i] = v;
    __syncthreads();
    #pragma unroll
    for (int off = 1; off < 1024; off <<= 1) {
        int t = (i >= off) ? tmp[i - off] : 0;
        __syncthreads();
        tmp[i] += t;
        __syncthreads();
    }
    if (i < K) {
        int base = tmp[i] - v;
        bucket_base[i] = base;
        bucket_cursor[i] = base;
    }
    if (i == K - 1) bucket_base[K] = tmp[i];
}

// ============ bucket fill: LDS bin-sort stage -> COALESCED run writes (R2-proven) ============

__global__ __launch_bounds__(256) void k_bfill(const int* __restrict__ src, const int* __restrict__ dst,
                                               int* __restrict__ bucket_cursor, unsigned int* __restrict__ bwords) {
    __shared__ int hist[K];
    __shared__ int ofs0[K];
    __shared__ int gb2[K];
    __shared__ int ptmp[256];
    __shared__ unsigned long long stage[CH];
    int tid = threadIdx.x;
    long e0 = (long)blockIdx.x * CH;
    int cnt = (int)min((long)CH, (long)NE - e0);

    for (int i = tid; i < K; i += 256) hist[i] = 0;
    __syncthreads();
    for (int i = tid; i < cnt; i += 256) atomicAdd(&hist[dst[e0 + i] >> 8], 1);
    __syncthreads();

    int b0 = tid * 4;
    int h0 = (b0 + 0 < K) ? hist[b0 + 0] : 0;
    int h1 = (b0 + 1 < K) ? hist[b0 + 1] : 0;
    int h2 = (b0 + 2 < K) ? hist[b0 + 2] : 0;
    int h3 = (b0 + 3 < K) ? hist[b0 + 3] : 0;
    int s = h0 + h1 + h2 + h3;
    ptmp[tid] = s;
    __syncthreads();
    #pragma unroll
    for (int off = 1; off < 256; off <<= 1) {
        int t = (tid >= off) ? ptmp[tid - off] : 0;
        __syncthreads();
        ptmp[tid] += t;
        __syncthreads();
    }
    int run = ptmp[tid] - s;
    if (b0 + 0 < K) { ofs0[b0 + 0] = run; run += h0; }
    if (b0 + 1 < K) { ofs0[b0 + 1] = run; run += h1; }
    if (b0 + 2 < K) { ofs0[b0 + 2] = run; run += h2; }
    if (b0 + 3 < K) { ofs0[b0 + 3] = run; run += h3; }
    __syncthreads();

    for (int b = tid; b < K; b += 256) {
        int h = hist[b];
        int g = h ? atomicAdd(&bucket_cursor[b], h) : 0;
        gb2[b] = g - ofs0[b];
    }
    __syncthreads();
    for (int b = tid; b < K; b += 256) hist[b] = 0;
    __syncthreads();

    for (int i = tid; i < cnt; i += 256) {
        int d = dst[e0 + i];
        int sv = src[e0 + i];
        int bin = d >> 8;
        int r = atomicAdd(&hist[bin], 1);
        unsigned int word = ((unsigned int)(d & 255) << 24) | (unsigned int)sv;  // src < 2^24
        stage[ofs0[bin] + r] = ((unsigned long long)(unsigned int)d << 32) | word;
    }
    __syncthreads();
    // coalesced: consecutive i -> consecutive bwords addresses within each run
    for (int i = tid; i < cnt; i += 256) {
        unsigned long long p = stage[i];
        int bin = (int)(p >> 40);
        bwords[gb2[bin] + i] = (unsigned int)p;
    }
}

// ============ per-bucket degree -> dinv (needed by gemm prescale) ============

__global__ __launch_bounds__(256) void k_deg(const unsigned int* __restrict__ bwords,
                                             const int* __restrict__ bucket_base, float* __restrict__ dinv) {
    __shared__ int cnt[256];
    int b = blockIdx.x;
    int tid = threadIdx.x;
    cnt[tid] = 0;
    __syncthreads();
    int p0 = bucket_base[b];
    int p1 = bucket_base[b + 1];
    for (int i = p0 + tid; i < p1; i += 256) atomicAdd(&cnt[bwords[i] >> 24], 1);
    __syncthreads();
    int n = (b << 8) + tid;
    if (n < NN) dinv[n] = rsqrtf((float)(cnt[tid] + 1));   // +1 self-loop
}

// ============ gemm1: h1s = fp16( (x @ W1) * dinv ) ============

__global__ __launch_bounds__(256) void k_gemm1(const float* __restrict__ x, const float* __restrict__ W1,
                                               const float* __restrict__ dinv, __half* __restrict__ h1s) {
    __shared__ float xs[KC][257];
    const int tid = threadIdx.x;
    const int row0 = blockIdx.x * 256;
    const int row = row0 + tid;
    float dv = (row < NN) ? dinv[row] : 1.f;
    float acc[HID];
    #pragma unroll
    for (int c = 0; c < HID; ++c) acc[c] = 0.f;

    for (int k0 = 0; k0 < FIN; k0 += KC) {
        __syncthreads();
        #pragma unroll
        for (int j = 0; j < 8; ++j) {
            int f = tid + 256 * j;
            int r = f >> 3;
            int kq = f & 7;
            int gr = row0 + r;
            float4 v = make_float4(0.f, 0.f, 0.f, 0.f);
            if (gr < NN) v = *(const float4*)(x + (size_t)gr * FIN + k0 + kq * 4);
            xs[kq * 4 + 0][r] = v.x;
            xs[kq * 4 + 1][r] = v.y;
            xs[kq * 4 + 2][r] = v.z;
            xs[kq * 4 + 3][r] = v.w;
        }
        __syncthreads();
        #pragma unroll 4
        for (int k = 0; k < KC; ++k) {
            float xv = xs[k][tid];
            const float4* w = (const float4*)(W1 + (size_t)(k0 + k) * HID);
            float4 w0 = w[0], w1 = w[1], w2 = w[2], w3 = w[3];
            acc[0]  = fmaf(xv, w0.x, acc[0]);  acc[1]  = fmaf(xv, w0.y, acc[1]);
            acc[2]  = fmaf(xv, w0.z, acc[2]);  acc[3]  = fmaf(xv, w0.w, acc[3]);
            acc[4]  = fmaf(xv, w1.x, acc[4]);  acc[5]  = fmaf(xv, w1.y, acc[5]);
            acc[6]  = fmaf(xv, w1.z, acc[6]);  acc[7]  = fmaf(xv, w1.w, acc[7]);
            acc[8]  = fmaf(xv, w2.x, acc[8]);  acc[9]  = fmaf(xv, w2.y, acc[9]);
            acc[10] = fmaf(xv, w2.z, acc[10]); acc[11] = fmaf(xv, w2.w, acc[11]);
            acc[12] = fmaf(xv, w3.x, acc[12]); acc[13] = fmaf(xv, w3.y, acc[13]);
            acc[14] = fmaf(xv, w3.z, acc[14]); acc[15] = fmaf(xv, w3.w, acc[15]);
        }
    }
    if (row < NN) {
        uint4 u0, u1;
        u0.x = f2h(acc[0]  * dv, acc[1]  * dv); u0.y = f2h(acc[2]  * dv, acc[3]  * dv);
        u0.z = f2h(acc[4]  * dv, acc[5]  * dv); u0.w = f2h(acc[6]  * dv, acc[7]  * dv);
        u1.x = f2h(acc[8]  * dv, acc[9]  * dv); u1.y = f2h(acc[10] * dv, acc[11] * dv);
        u1.z = f2h(acc[12] * dv, acc[13] * dv); u1.w = f2h(acc[14] * dv, acc[15] * dv);
        uint4* o = (uint4*)(h1s + (size_t)row * HID);
        o[0] = u0; o[1] = u1;
    }
}

// ============ agg1: per-bucket LDS sort + thread-per-node gather + epilogue ============
// pass1: read bucket slice + LDS hist; scan; pass2: re-read (L2-warm) + scatter sorted src
// into 40KB LDS; then each thread gathers its node's fp16 rows. ~4 LDS ops/edge (vs R4's 16 atomics).

__device__ __forceinline__ void accrow16(float* A, uint4 a, uint4 b) {
    float2 f;
    f = h2f(a.x); A[0]  += f.x; A[1]  += f.y;
    f = h2f(a.y); A[2]  += f.x; A[3]  += f.y;
    f = h2f(a.z); A[4]  += f.x; A[5]  += f.y;
    f = h2f(a.w); A[6]  += f.x; A[7]  += f.y;
    f = h2f(b.x); A[8]  += f.x; A[9]  += f.y;
    f = h2f(b.y); A[10] += f.x; A[11] += f.y;
    f = h2f(b.z); A[12] += f.x; A[13] += f.y;
    f = h2f(b.w); A[14] += f.x; A[15] += f.y;
}

__global__ __launch_bounds__(256) void k_agg1c(const unsigned int* __restrict__ bwords,
                                               const int* __restrict__ bucket_base,
                                               const __half* __restrict__ h1s,
                                               const float* __restrict__ b1, const float* __restrict__ W2,
                                               __half* __restrict__ h2s) {
    __shared__ int cnt[256];
    __shared__ int st[256];
    __shared__ unsigned int ew[WMAX];
    int b = blockIdx.x;
    int tid = threadIdx.x;
    int p0 = bucket_base[b];
    int m = min(bucket_base[b + 1] - p0, WMAX);

    cnt[tid] = 0;
    __syncthreads();
    for (int i = tid; i < m; i += 256) atomicAdd(&cnt[bwords[p0 + i] >> 24], 1);
    __syncthreads();
    int v = cnt[tid];
    st[tid] = v;
    __syncthreads();
    #pragma unroll
    for (int off = 1; off < 256; off <<= 1) {
        int t = (tid >= off) ? st[tid - off] : 0;
        __syncthreads();
        st[tid] += t;
        __syncthreads();
    }
    int myst = st[tid] - v;
    __syncthreads();
    st[tid] = myst;
    cnt[tid] = 0;
    __syncthreads();
    for (int i = tid; i < m; i += 256) {
        unsigned int w = bwords[p0 + i];        // L1/L2-warm re-read
        int loc = w >> 24;
        int r = atomicAdd(&cnt[loc], 1);
        ew[st[loc] + r] = w & 0xFFFFFFu;
    }
    __syncthreads();

    int n = (b << 8) + tid;
    if (n >= NN) return;
    float acc[HID];
    {   // self-loop init from own (prescaled) row
        const uint4* q = (const uint4*)(h1s + (size_t)n * HID);
        uint4 a = q[0], bb = q[1];
        float2 f;
        f = h2f(a.x);  acc[0]  = f.x; acc[1]  = f.y;
        f = h2f(a.y);  acc[2]  = f.x; acc[3]  = f.y;
        f = h2f(a.z);  acc[4]  = f.x; acc[5]  = f.y;
        f = h2f(a.w);  acc[6]  = f.x; acc[7]  = f.y;
        f = h2f(bb.x); acc[8]  = f.x; acc[9]  = f.y;
        f = h2f(bb.y); acc[10] = f.x; acc[11] = f.y;
        f = h2f(bb.z); acc[12] = f.x; acc[13] = f.y;
        f = h2f(bb.w); acc[14] = f.x; acc[15] = f.y;
    }
    int j = 0;
    for (; j + 1 < v; j += 2) {
        int s0 = ew[myst + j];
        int s1 = ew[myst + j + 1];
        const uint4* P0 = (const uint4*)(h1s + (size_t)s0 * HID);
        const uint4* P1 = (const uint4*)(h1s + (size_t)s1 * HID);
        uint4 a0 = P0[0], b0 = P0[1], a1 = P1[0], b1v = P1[1];
        accrow16(acc, a0, b0);
        accrow16(acc, a1, b1v);
    }
    if (j < v) {
        int s0 = ew[myst + j];
        const uint4* P0 = (const uint4*)(h1s + (size_t)s0 * HID);
        uint4 a0 = P0[0], b0 = P0[1];
        accrow16(acc, a0, b0);
    }

    float dv = rsqrtf((float)(v + 1));          // bit-identical to k_deg's dinv
    float h[HID];
    #pragma unroll
    for (int c = 0; c < HID; ++c) h[c] = fmaxf(fmaf(dv, acc[c], b1[c]), 0.f);
    float z[8];
    #pragma unroll
    for (int jj = 0; jj < NC; ++jj) {
        float t = 0.f;
        #pragma unroll
        for (int c = 0; c < HID; ++c) t = fmaf(h[c], W2[c * NC + jj], t);
        z[jj] = t * dv;
    }
    z[7] = 0.f;
    uint4 u;
    u.x = f2h(z[0], z[1]); u.y = f2h(z[2], z[3]); u.z = f2h(z[4], z[5]); u.w = f2h(z[6], z[7]);
    *(uint4*)(h2s + (size_t)n * 8) = u;
}

// ============ agg2: same structure, 16B rows, fp32 out ============

__global__ __launch_bounds__(256) void k_agg2c(const unsigned int* __restrict__ bwords,
                                               const int* __restrict__ bucket_base,
                                               const __half* __restrict__ h2s,
                                               const float* __restrict__ b2, float* __restrict__ out) {
    __shared__ int cnt[256];
    __shared__ int st[256];
    __shared__ unsigned int ew[WMAX];
    int b = blockIdx.x;
    int tid = threadIdx.x;
    int p0 = bucket_base[b];
    int m = min(bucket_base[b + 1] - p0, WMAX);

    cnt[tid] = 0;
    __syncthreads();
    for (int i = tid; i < m; i += 256) atomicAdd(&cnt[bwords[p0 + i] >> 24], 1);
    __syncthreads();
    int v = cnt[tid];
    st[tid] = v;
    __syncthreads();
    #pragma unroll
    for (int off = 1; off < 256; off <<= 1) {
        int t = (tid >= off) ? st[tid - off] : 0;
        __syncthreads();
        st[tid] += t;
        __syncthreads();
    }
    int myst = st[tid] - v;
    __syncthreads();
    st[tid] = myst;
    cnt[tid] = 0;
    __syncthreads();
    for (int i = tid; i < m; i += 256) {
        unsigned int w = bwords[p0 + i];
        int loc = w >> 24;
        int r = atomicAdd(&cnt[loc], 1);
        ew[st[loc] + r] = w & 0xFFFFFFu;
    }
    __syncthreads();

    int n = (b << 8) + tid;
    if (n >= NN) return;
    float A[8];
    {
        uint4 a = *(const uint4*)(h2s + (size_t)n * 8);
        float2 f;
        f = h2f(a.x); A[0] = f.x; A[1] = f.y;
        f = h2f(a.y); A[2] = f.x; A[3] = f.y;
        f = h2f(a.z); A[4] = f.x; A[5] = f.y;
        f = h2f(a.w); A[6] = f.x; A[7] = f.y;
    }
    int j = 0;
    for (; j + 1 < v; j += 2) {
        int s0 = ew[myst + j];
        int s1 = ew[myst + j + 1];
        uint4 a = *(const uint4*)(h2s + (size_t)s0 * 8);
        uint4 c = *(const uint4*)(h2s + (size_t)s1 * 8);
        float2 f;
        f = h2f(a.x); A[0] += f.x; A[1] += f.y;
        f = h2f(a.y); A[2] += f.x; A[3] += f.y;
        f = h2f(a.z); A[4] += f.x; A[5] += f.y;
        f = h2f(a.w); A[6] += f.x;
        f = h2f(c.x); A[0] += f.x; A[1] += f.y;
        f = h2f(c.y); A[2] += f.x; A[3] += f.y;
        f = h2f(c.z); A[4] += f.x; A[5] += f.y;
        f = h2f(c.w); A[6] += f.x;
    }
    if (j < v) {
        int s0 = ew[myst + j];
        uint4 a = *(const uint4*)(h2s + (size_t)s0 * 8);
        float2 f;
        f = h2f(a.x); A[0] += f.x; A[1] += f.y;
        f = h2f(a.y); A[2] += f.x; A[3] += f.y;
        f = h2f(a.z); A[4] += f.x; A[5] += f.y;
        f = h2f(a.w); A[6] += f.x;
    }
    float dv = rsqrtf((float)(v + 1));
    #pragma unroll
    for (int jj = 0; jj < NC; ++jj) out[(size_t)n * NC + jj] = fmaf(dv, A[jj], b2[jj]);
}

// ============ launch ============

extern "C" void kernel_launch(void* const* d_in, const int* in_sizes, int n_in,
                              void* d_out, int out_size, void* d_ws, size_t ws_size,
                              hipStream_t stream) {
    const float* x  = (const float*)d_in[0];
    const int*   ei = (const int*)d_in[1];
    const float* W1 = (const float*)d_in[2];
    const float* b1 = (const float*)d_in[3];
    const float* W2 = (const float*)d_in[4];
    const float* b2 = (const float*)d_in[5];
    const int* src = ei;
    const int* dst = ei + NE;
    float* out = (float*)d_out;

    char* ws = (char*)d_ws;
    size_t o = 0;
    auto alloc = [&](size_t bytes) {
        char* p = ws + o;
        o = (o + bytes + 255) & ~(size_t)255;
        return p;
    };
    int*   bucket_total  = (int*)alloc((size_t)(K + 1) * 4);
    int*   bucket_base   = (int*)alloc((size_t)(K + 1) * 4);
    int*   bucket_cursor = (int*)alloc((size_t)(K + 1) * 4);
    unsigned int* bwords = (unsigned int*)alloc((size_t)NE * 4);
    float* dinv  = (float*)alloc((size_t)NN * 4);
    __half* h1s  = (__half*)alloc((size_t)NN * HID * 2);
    __half* h2s  = (__half*)alloc((size_t)NN * 8 * 2);

    hipMemsetAsync(bucket_total, 0, (size_t)(K + 1) * 4, stream);
    k_bcount<<<EB, 256, 0, stream>>>(dst, bucket_total);
    k_bscan <<<1, 1024, 0, stream>>>(bucket_total, bucket_base, bucket_cursor);
    k_bfill <<<EB, 256, 0, stream>>>(src, dst, bucket_cursor, bwords);
    k_deg   <<<K, 256, 0, stream>>>(bwords, bucket_base, dinv);
    k_gemm1 <<<NB, 256, 0, stream>>>(x, W1, dinv, h1s);
    k_agg1c <<<K, 256, 0, stream>>>(bwords, bucket_base, h1s, b1, W2, h2s);
    k_agg2c <<<K, 256, 0, stream>>>(bwords, bucket_base, h2s, b2, out);
}